// Round 1
// baseline (512.259 us; speedup 1.0000x reference)
//
#include <hip/hip_runtime.h>
#include <hip/hip_bf16.h>
#include <float.h>

#define B_ 4
#define NH_ 32
#define NKV_ 8
#define D_ 128
#define S_ 16384
#define L_ 16385
#define H_ 4096
#define INIT_ 128
#define LOCAL_ 128
#define HEAVY_ 2048
#define CHUNK_ 2048
#define NCHUNK_ 9   // ceil(16385/2048)

__device__ __forceinline__ unsigned f2key(float f) {
  unsigned u = __float_as_uint(f);
  return (u & 0x80000000u) ? ~u : (u | 0x80000000u);
}
__device__ __forceinline__ float key2f(unsigned k) {
  unsigned u = (k & 0x80000000u) ? (k & 0x7FFFFFFFu) : ~k;
  return __uint_as_float(u);
}

// ---------------- Kernel A: q/k/v projections (one wave per output row, 4 batches) ----
__global__ __launch_bounds__(256) void k_proj(const float* __restrict__ hs,
    const float* __restrict__ Wq, const float* __restrict__ Wk, const float* __restrict__ Wv,
    float* __restrict__ qraw, float* __restrict__ kraw, float* __restrict__ vnew) {
  int gw = (blockIdx.x * 256 + threadIdx.x) >> 6;   // 0..6143
  int lane = threadIdx.x & 63;
  const float* W;
  if (gw < 4096)      W = Wq + (size_t)gw * H_;
  else if (gw < 5120) W = Wk + (size_t)(gw - 4096) * H_;
  else                W = Wv + (size_t)(gw - 5120) * H_;
  float a0 = 0.f, a1 = 0.f, a2 = 0.f, a3 = 0.f;
  #pragma unroll 4
  for (int it = 0; it < 16; ++it) {
    int h = it * 256 + lane * 4;
    float4 w4 = *(const float4*)(W + h);
    float4 x0 = *(const float4*)(hs + 0 * H_ + h);
    float4 x1 = *(const float4*)(hs + 1 * H_ + h);
    float4 x2 = *(const float4*)(hs + 2 * H_ + h);
    float4 x3 = *(const float4*)(hs + 3 * H_ + h);
    a0 += w4.x * x0.x + w4.y * x0.y + w4.z * x0.z + w4.w * x0.w;
    a1 += w4.x * x1.x + w4.y * x1.y + w4.z * x1.z + w4.w * x1.w;
    a2 += w4.x * x2.x + w4.y * x2.y + w4.z * x2.z + w4.w * x2.w;
    a3 += w4.x * x3.x + w4.y * x3.y + w4.z * x3.z + w4.w * x3.w;
  }
  #pragma unroll
  for (int m = 1; m < 64; m <<= 1) {
    a0 += __shfl_xor(a0, m);
    a1 += __shfl_xor(a1, m);
    a2 += __shfl_xor(a2, m);
    a3 += __shfl_xor(a3, m);
  }
  if (lane < 4) {
    float v = (lane == 0) ? a0 : (lane == 1) ? a1 : (lane == 2) ? a2 : a3;
    if (gw < 4096)      qraw[(size_t)lane * H_ + gw] = v;
    else if (gw < 5120) kraw[(size_t)lane * 1024 + (gw - 4096)] = v;
    else                vnew[(size_t)lane * 1024 + (gw - 5120)] = v;
  }
}

// ---------------- Kernel B: RoPE on q and k_new (separate out buffers, no race) -------
__global__ __launch_bounds__(128) void k_rope(const float* __restrict__ qraw,
    const float* __restrict__ kraw, const float* __restrict__ cosv, const float* __restrict__ sinv,
    float* __restrict__ qrot, float* __restrict__ krot) {
  int bid = blockIdx.x;            // 0..159
  int b = bid / 40, r = bid % 40;
  int d = threadIdx.x;             // 0..127
  const float* src; float* dst;
  if (r < 32) { src = qraw + (size_t)b * H_ + r * 128; dst = qrot + (size_t)b * H_ + r * 128; }
  else { int kv = r - 32; src = kraw + (size_t)b * 1024 + kv * 128; dst = krot + (size_t)b * 1024 + kv * 128; }
  float x = src[d];
  float p = (d < 64) ? -src[d + 64] : src[d - 64];
  dst[d] = x * cosv[d] + p * sinv[d];
}

// ---------------- Kernel C: scores with 4-bit pseudo-quantized K ----------------------
// half-wave (32 lanes, float4 each) per K row; 4 GQA heads' dots per row.
__global__ __launch_bounds__(256) void k_scores(const float* __restrict__ kcache,
    const float* __restrict__ krot, const float* __restrict__ qrot,
    float* __restrict__ scores) {
  int wave = threadIdx.x >> 6, lane = threadIdx.x & 63;
  int half = lane >> 5, sub = lane & 31;
  int bkv = blockIdx.y; int b = bkv >> 3, kv = bkv & 7;
  __shared__ __align__(16) float qsh[512];
  for (int i = threadIdx.x; i < 512; i += 256)
    qsh[i] = qrot[(size_t)b * H_ + kv * 512 + i];
  __syncthreads();
  int base = blockIdx.x * 512;
  const float* kbase = kcache + ((size_t)(b * NKV_ + kv) * S_) * D_;
  const float* knrow = krot + (size_t)(b * NKV_ + kv) * D_;
  for (int it = 0; it < 64; ++it) {
    int l = base + it * 8 + wave * 2 + half;
    if (l >= L_) continue;
    const float* krow = (l < S_) ? (kbase + (size_t)l * D_) : knrow;
    float4 kx = *(const float4*)(krow + sub * 4);
    float mn = fminf(fminf(kx.x, kx.y), fminf(kx.z, kx.w));
    float mx = fmaxf(fmaxf(kx.x, kx.y), fmaxf(kx.z, kx.w));
    #pragma unroll
    for (int m = 1; m <= 16; m <<= 1) {
      mn = fminf(mn, __shfl_xor(mn, m));
      mx = fmaxf(mx, __shfl_xor(mx, m));
    }
    float rng = mx - mn; rng = (rng == 0.0f) ? 1.0f : rng;
    float scale = 15.0f / rng;          // IEEE divide: match reference rint boundaries
    float s2 = rng * (1.0f / 15.0f);
    float dx = fmaf(fminf(fmaxf(rintf((kx.x - mn) * scale), 0.0f), 15.0f), s2, mn);
    float dy = fmaf(fminf(fmaxf(rintf((kx.y - mn) * scale), 0.0f), 15.0f), s2, mn);
    float dz = fmaf(fminf(fmaxf(rintf((kx.z - mn) * scale), 0.0f), 15.0f), s2, mn);
    float dw = fmaf(fminf(fmaxf(rintf((kx.w - mn) * scale), 0.0f), 15.0f), s2, mn);
    float dot0, dot1, dot2, dot3;
    {
      float4 qv = *(const float4*)(qsh + 0 * 128 + sub * 4);
      dot0 = dx * qv.x + dy * qv.y + dz * qv.z + dw * qv.w;
    }
    {
      float4 qv = *(const float4*)(qsh + 1 * 128 + sub * 4);
      dot1 = dx * qv.x + dy * qv.y + dz * qv.z + dw * qv.w;
    }
    {
      float4 qv = *(const float4*)(qsh + 2 * 128 + sub * 4);
      dot2 = dx * qv.x + dy * qv.y + dz * qv.z + dw * qv.w;
    }
    {
      float4 qv = *(const float4*)(qsh + 3 * 128 + sub * 4);
      dot3 = dx * qv.x + dy * qv.y + dz * qv.z + dw * qv.w;
    }
    #pragma unroll
    for (int m = 1; m <= 16; m <<= 1) {
      dot0 += __shfl_xor(dot0, m);
      dot1 += __shfl_xor(dot1, m);
      dot2 += __shfl_xor(dot2, m);
      dot3 += __shfl_xor(dot3, m);
    }
    if (sub < 4) {
      float v = (sub == 0) ? dot0 : (sub == 1) ? dot1 : (sub == 2) ? dot2 : dot3;
      scores[((size_t)(b * NH_ + kv * 4 + sub)) * L_ + l] = v * 0.08838834764831845f;
    }
  }
}

// ---------------- Kernel D: exact 2048th-largest via 3-pass radix select + row max ----
__global__ __launch_bounds__(256) void k_topk(const float* __restrict__ scores,
    float* __restrict__ kthM) {
  int row = blockIdx.x;                 // b*32+h
  const float* srow = scores + (size_t)row * L_;
  __shared__ unsigned bins[4096];
  __shared__ float smax[256];
  __shared__ unsigned chs[256];
  __shared__ unsigned sel_digit, sel_rank;
  int tid = threadIdx.x;

  // ---- pass 1: top 12 bits, plus global row max ----
  for (int i = tid; i < 4096; i += 256) bins[i] = 0;
  __syncthreads();
  float lm = -FLT_MAX;
  for (int l = tid; l < L_; l += 256) {
    float s = srow[l];
    lm = fmaxf(lm, s);
    bool always = (l < INIT_) || (l >= L_ - LOCAL_);
    if (!always) atomicAdd(&bins[f2key(s) >> 20], 1u);
  }
  smax[tid] = lm;
  __syncthreads();
  for (int off = 128; off > 0; off >>= 1) {
    if (tid < off) smax[tid] = fmaxf(smax[tid], smax[tid + off]);
    __syncthreads();
  }
  unsigned c = 0;
  for (int j = 0; j < 16; ++j) c += bins[tid * 16 + j];
  chs[tid] = c;
  __syncthreads();
  if (tid == 0) {
    unsigned K = HEAVY_, cum = 0; int cc = 255;
    for (; cc >= 0; --cc) { cum += chs[cc]; if (cum >= K) break; }
    unsigned rem = K - (cum - chs[cc]);
    unsigned cum2 = 0; int bb = cc * 16;
    for (int j = 15; j >= 0; --j) {
      cum2 += bins[cc * 16 + j];
      if (cum2 >= rem) { bb = cc * 16 + j; rem = rem - (cum2 - bins[cc * 16 + j]); break; }
    }
    sel_digit = (unsigned)bb; sel_rank = rem;
  }
  __syncthreads();
  unsigned d1 = sel_digit, K2 = sel_rank;
  __syncthreads();

  // ---- pass 2: bits 19:8 within d1 ----
  for (int i = tid; i < 4096; i += 256) bins[i] = 0;
  __syncthreads();
  for (int l = tid; l < L_; l += 256) {
    bool always = (l < INIT_) || (l >= L_ - LOCAL_);
    if (always) continue;
    unsigned u = f2key(srow[l]);
    if ((u >> 20) == d1) atomicAdd(&bins[(u >> 8) & 0xFFFu], 1u);
  }
  __syncthreads();
  c = 0;
  for (int j = 0; j < 16; ++j) c += bins[tid * 16 + j];
  chs[tid] = c;
  __syncthreads();
  if (tid == 0) {
    unsigned K = K2, cum = 0; int cc = 255;
    for (; cc >= 0; --cc) { cum += chs[cc]; if (cum >= K) break; }
    unsigned rem = K - (cum - chs[cc]);
    unsigned cum2 = 0; int bb = cc * 16;
    for (int j = 15; j >= 0; --j) {
      cum2 += bins[cc * 16 + j];
      if (cum2 >= rem) { bb = cc * 16 + j; rem = rem - (cum2 - bins[cc * 16 + j]); break; }
    }
    sel_digit = (unsigned)bb; sel_rank = rem;
  }
  __syncthreads();
  unsigned d2 = sel_digit, K3 = sel_rank;
  __syncthreads();

  // ---- pass 3: low 8 bits within (d1,d2) ----
  for (int i = tid; i < 4096; i += 256) bins[i] = 0;
  __syncthreads();
  unsigned pref = (d1 << 12) | d2;
  for (int l = tid; l < L_; l += 256) {
    bool always = (l < INIT_) || (l >= L_ - LOCAL_);
    if (always) continue;
    unsigned u = f2key(srow[l]);
    if ((u >> 8) == pref) atomicAdd(&bins[u & 0xFFu], 1u);
  }
  __syncthreads();
  if (tid == 0) {
    unsigned cum = 0; int bb = 0;
    for (int j = 255; j >= 0; --j) { cum += bins[j]; if (cum >= K3) { bb = j; break; } }
    unsigned ku = (d1 << 20) | (d2 << 8) | (unsigned)bb;
    kthM[row * 2 + 0] = key2f(ku);
    kthM[row * 2 + 1] = smax[0];
  }
}

// ---------------- Kernel E2: softmax-weighted dequantized-V accumulation (chunked) ----
__global__ __launch_bounds__(256) void k_pv(const float* __restrict__ scores,
    const float* __restrict__ kthM, const float* __restrict__ vcache,
    const float* __restrict__ vnew, float* __restrict__ partials) {
  int chunk = blockIdx.x, row = blockIdx.y;
  int b = row >> 5, h = row & 31, kv = h >> 2;
  int wave = threadIdx.x >> 6, lane = threadIdx.x & 63;
  float kth = kthM[row * 2 + 0], M = kthM[row * 2 + 1];
  const float* srow = scores + (size_t)row * L_;
  const float* vbase = vcache + ((size_t)(b * NKV_ + kv) * S_) * D_;
  const float* vnrow = vnew + (size_t)(b * NKV_ + kv) * D_;
  int end = min(chunk * CHUNK_ + CHUNK_, L_);
  float ax = 0.f, ay = 0.f, z = 0.f;
  for (int l = chunk * CHUNK_ + wave; l < end; l += 4) {
    float s = srow[l];
    bool keep = (l < INIT_) || (l >= L_ - LOCAL_) || (s >= kth);
    if (!keep) continue;
    const float* vrow = (l < S_) ? (vbase + (size_t)l * D_) : vnrow;
    float2 v = *(const float2*)(vrow + lane * 2);
    float mn = fminf(v.x, v.y), mx = fmaxf(v.x, v.y);
    #pragma unroll
    for (int m = 1; m <= 32; m <<= 1) {
      mn = fminf(mn, __shfl_xor(mn, m));
      mx = fmaxf(mx, __shfl_xor(mx, m));
    }
    float rng = mx - mn; rng = (rng == 0.0f) ? 1.0f : rng;
    float scale = 15.0f / rng;
    float s2 = rng * (1.0f / 15.0f);
    float w = expf(s - M);
    float vx = fmaf(fminf(fmaxf(rintf((v.x - mn) * scale), 0.0f), 15.0f), s2, mn);
    float vy = fmaf(fminf(fmaxf(rintf((v.y - mn) * scale), 0.0f), 15.0f), s2, mn);
    ax = fmaf(w, vx, ax);
    ay = fmaf(w, vy, ay);
    z += w;
  }
  __shared__ float sacc[4][128];
  __shared__ float szs[4];
  sacc[wave][lane * 2] = ax;
  sacc[wave][lane * 2 + 1] = ay;
  if (lane == 0) szs[wave] = z;
  __syncthreads();
  int tid = threadIdx.x;
  float* prow = partials + ((size_t)row * NCHUNK_ + chunk) * 129;
  if (tid < 128) prow[tid] = sacc[0][tid] + sacc[1][tid] + sacc[2][tid] + sacc[3][tid];
  else if (tid == 128) prow[128] = szs[0] + szs[1] + szs[2] + szs[3];
}

// ---------------- Kernel E3: deterministic chunk reduce + normalize -------------------
__global__ __launch_bounds__(128) void k_fin(const float* __restrict__ partials,
    float* __restrict__ attn) {
  int row = blockIdx.x, d = threadIdx.x;
  float a = 0.f, z = 0.f;
  for (int c = 0; c < NCHUNK_; ++c) {
    const float* p = partials + ((size_t)row * NCHUNK_ + c) * 129;
    a += p[d];
    z += p[128];
  }
  attn[(size_t)row * 128 + d] = a / z;
}

// ---------------- Kernel F: output projection -----------------------------------------
__global__ __launch_bounds__(256) void k_out(const float* __restrict__ attn,
    const float* __restrict__ Wo, float* __restrict__ out) {
  int gw = (blockIdx.x * 256 + threadIdx.x) >> 6;   // 0..4095
  int lane = threadIdx.x & 63;
  const float* W = Wo + (size_t)gw * H_;
  float a0 = 0.f, a1 = 0.f, a2 = 0.f, a3 = 0.f;
  #pragma unroll 4
  for (int it = 0; it < 16; ++it) {
    int i = it * 256 + lane * 4;
    float4 w4 = *(const float4*)(W + i);
    float4 x0 = *(const float4*)(attn + 0 * H_ + i);
    float4 x1 = *(const float4*)(attn + 1 * H_ + i);
    float4 x2 = *(const float4*)(attn + 2 * H_ + i);
    float4 x3 = *(const float4*)(attn + 3 * H_ + i);
    a0 += w4.x * x0.x + w4.y * x0.y + w4.z * x0.z + w4.w * x0.w;
    a1 += w4.x * x1.x + w4.y * x1.y + w4.z * x1.z + w4.w * x1.w;
    a2 += w4.x * x2.x + w4.y * x2.y + w4.z * x2.z + w4.w * x2.w;
    a3 += w4.x * x3.x + w4.y * x3.y + w4.z * x3.z + w4.w * x3.w;
  }
  #pragma unroll
  for (int m = 1; m < 64; m <<= 1) {
    a0 += __shfl_xor(a0, m);
    a1 += __shfl_xor(a1, m);
    a2 += __shfl_xor(a2, m);
    a3 += __shfl_xor(a3, m);
  }
  if (lane < 4) {
    float v = (lane == 0) ? a0 : (lane == 1) ? a1 : (lane == 2) ? a2 : a3;
    out[(size_t)lane * H_ + gw] = v;
  }
}

extern "C" void kernel_launch(void* const* d_in, const int* in_sizes, int n_in,
                              void* d_out, int out_size, void* d_ws, size_t ws_size,
                              hipStream_t stream) {
  const float* hs     = (const float*)d_in[0];
  const float* kcache = (const float*)d_in[1];
  const float* vcache = (const float*)d_in[2];
  const float* cosv   = (const float*)d_in[3];
  const float* sinv   = (const float*)d_in[4];
  const float* Wq     = (const float*)d_in[5];
  const float* Wk     = (const float*)d_in[6];
  const float* Wv     = (const float*)d_in[7];
  const float* Wo     = (const float*)d_in[8];
  float* out = (float*)d_out;

  float* ws = (float*)d_ws;
  float* qraw     = ws;                      // 16384
  float* kraw     = qraw + 16384;            // 4096
  float* vnew     = kraw + 4096;             // 4096
  float* qrot     = vnew + 4096;             // 16384
  float* krot     = qrot + 16384;            // 4096
  float* scores   = krot + 4096;             // 4*32*16385 = 2097280
  float* kthM     = scores + 2097280;        // 256
  float* partials = kthM + 256;              // 128*9*129 = 148608
  float* attn     = partials + 148608;       // 16384
  (void)in_sizes; (void)n_in; (void)out_size; (void)ws_size; (void)attn;

  hipLaunchKernelGGL(k_proj,   dim3(1536),   dim3(256), 0, stream, hs, Wq, Wk, Wv, qraw, kraw, vnew);
  hipLaunchKernelGGL(k_rope,   dim3(160),    dim3(128), 0, stream, qraw, kraw, cosv, sinv, qrot, krot);
  hipLaunchKernelGGL(k_scores, dim3(33, 32), dim3(256), 0, stream, kcache, krot, qrot, scores);
  hipLaunchKernelGGL(k_topk,   dim3(128),    dim3(256), 0, stream, scores, kthM);
  hipLaunchKernelGGL(k_pv,     dim3(NCHUNK_, 128), dim3(256), 0, stream, scores, kthM, vcache, vnew, partials);
  hipLaunchKernelGGL(k_fin,    dim3(128),    dim3(128), 0, stream, partials, attn);
  hipLaunchKernelGGL(k_out,    dim3(1024),   dim3(256), 0, stream, attn, Wo, out);
}

// Round 2
// 308.346 us; speedup vs baseline: 1.6613x; 1.6613x over previous
//
#include <hip/hip_runtime.h>
#include <hip/hip_bf16.h>
#include <float.h>

#define B_ 4
#define NH_ 32
#define NKV_ 8
#define D_ 128
#define S_ 16384
#define L_ 16385
#define H_ 4096
#define INIT_ 128
#define LOCAL_ 128
#define HEAVY_ 2048
#define CHUNK_ 2048
#define NCHUNK_ 9   // ceil(16385/2048)

__device__ __forceinline__ unsigned f2key(float f) {
  unsigned u = __float_as_uint(f);
  return (u & 0x80000000u) ? ~u : (u | 0x80000000u);
}
__device__ __forceinline__ float key2f(unsigned k) {
  unsigned u = (k & 0x80000000u) ? (k & 0x7FFFFFFFu) : ~k;
  return __uint_as_float(u);
}

// ---------------- Kernel A: q/k/v projections (one wave per output row, 4 batches) ----
__global__ __launch_bounds__(256) void k_proj(const float* __restrict__ hs,
    const float* __restrict__ Wq, const float* __restrict__ Wk, const float* __restrict__ Wv,
    float* __restrict__ qraw, float* __restrict__ kraw, float* __restrict__ vnew) {
  int gw = (blockIdx.x * 256 + threadIdx.x) >> 6;   // 0..6143
  int lane = threadIdx.x & 63;
  const float* W;
  if (gw < 4096)      W = Wq + (size_t)gw * H_;
  else if (gw < 5120) W = Wk + (size_t)(gw - 4096) * H_;
  else                W = Wv + (size_t)(gw - 5120) * H_;
  float a0 = 0.f, a1 = 0.f, a2 = 0.f, a3 = 0.f;
  #pragma unroll 4
  for (int it = 0; it < 16; ++it) {
    int h = it * 256 + lane * 4;
    float4 w4 = *(const float4*)(W + h);
    float4 x0 = *(const float4*)(hs + 0 * H_ + h);
    float4 x1 = *(const float4*)(hs + 1 * H_ + h);
    float4 x2 = *(const float4*)(hs + 2 * H_ + h);
    float4 x3 = *(const float4*)(hs + 3 * H_ + h);
    a0 += w4.x * x0.x + w4.y * x0.y + w4.z * x0.z + w4.w * x0.w;
    a1 += w4.x * x1.x + w4.y * x1.y + w4.z * x1.z + w4.w * x1.w;
    a2 += w4.x * x2.x + w4.y * x2.y + w4.z * x2.z + w4.w * x2.w;
    a3 += w4.x * x3.x + w4.y * x3.y + w4.z * x3.z + w4.w * x3.w;
  }
  #pragma unroll
  for (int m = 1; m < 64; m <<= 1) {
    a0 += __shfl_xor(a0, m);
    a1 += __shfl_xor(a1, m);
    a2 += __shfl_xor(a2, m);
    a3 += __shfl_xor(a3, m);
  }
  if (lane < 4) {
    float v = (lane == 0) ? a0 : (lane == 1) ? a1 : (lane == 2) ? a2 : a3;
    if (gw < 4096)      qraw[(size_t)lane * H_ + gw] = v;
    else if (gw < 5120) kraw[(size_t)lane * 1024 + (gw - 4096)] = v;
    else                vnew[(size_t)lane * 1024 + (gw - 5120)] = v;
  }
}

// ---------------- Kernel B: RoPE on q and k_new (separate out buffers, no race) -------
__global__ __launch_bounds__(128) void k_rope(const float* __restrict__ qraw,
    const float* __restrict__ kraw, const float* __restrict__ cosv, const float* __restrict__ sinv,
    float* __restrict__ qrot, float* __restrict__ krot) {
  int bid = blockIdx.x;            // 0..159
  int b = bid / 40, r = bid % 40;
  int d = threadIdx.x;             // 0..127
  const float* src; float* dst;
  if (r < 32) { src = qraw + (size_t)b * H_ + r * 128; dst = qrot + (size_t)b * H_ + r * 128; }
  else { int kv = r - 32; src = kraw + (size_t)b * 1024 + kv * 128; dst = krot + (size_t)b * 1024 + kv * 128; }
  float x = src[d];
  float p = (d < 64) ? -src[d + 64] : src[d - 64];
  dst[d] = x * cosv[d] + p * sinv[d];
}

// ---------------- Kernel C: scores with 4-bit pseudo-quantized K ----------------------
// half-wave (32 lanes, float4 each) per K row; 4 GQA heads' dots per row.
__global__ __launch_bounds__(256) void k_scores(const float* __restrict__ kcache,
    const float* __restrict__ krot, const float* __restrict__ qrot,
    float* __restrict__ scores) {
  int wave = threadIdx.x >> 6, lane = threadIdx.x & 63;
  int half = lane >> 5, sub = lane & 31;
  int bkv = blockIdx.y; int b = bkv >> 3, kv = bkv & 7;
  __shared__ __align__(16) float qsh[512];
  for (int i = threadIdx.x; i < 512; i += 256)
    qsh[i] = qrot[(size_t)b * H_ + kv * 512 + i];
  __syncthreads();
  int base = blockIdx.x * 512;
  const float* kbase = kcache + ((size_t)(b * NKV_ + kv) * S_) * D_;
  const float* knrow = krot + (size_t)(b * NKV_ + kv) * D_;
  for (int it = 0; it < 64; ++it) {
    int l = base + it * 8 + wave * 2 + half;
    if (l >= L_) continue;
    const float* krow = (l < S_) ? (kbase + (size_t)l * D_) : knrow;
    float4 kx = *(const float4*)(krow + sub * 4);
    float mn = fminf(fminf(kx.x, kx.y), fminf(kx.z, kx.w));
    float mx = fmaxf(fmaxf(kx.x, kx.y), fmaxf(kx.z, kx.w));
    #pragma unroll
    for (int m = 1; m <= 16; m <<= 1) {
      mn = fminf(mn, __shfl_xor(mn, m));
      mx = fmaxf(mx, __shfl_xor(mx, m));
    }
    float rng = mx - mn; rng = (rng == 0.0f) ? 1.0f : rng;
    float scale = 15.0f / rng;          // IEEE divide: match reference rint boundaries
    float s2 = rng * (1.0f / 15.0f);
    float dx = fmaf(fminf(fmaxf(rintf((kx.x - mn) * scale), 0.0f), 15.0f), s2, mn);
    float dy = fmaf(fminf(fmaxf(rintf((kx.y - mn) * scale), 0.0f), 15.0f), s2, mn);
    float dz = fmaf(fminf(fmaxf(rintf((kx.z - mn) * scale), 0.0f), 15.0f), s2, mn);
    float dw = fmaf(fminf(fmaxf(rintf((kx.w - mn) * scale), 0.0f), 15.0f), s2, mn);
    float dot0, dot1, dot2, dot3;
    {
      float4 qv = *(const float4*)(qsh + 0 * 128 + sub * 4);
      dot0 = dx * qv.x + dy * qv.y + dz * qv.z + dw * qv.w;
    }
    {
      float4 qv = *(const float4*)(qsh + 1 * 128 + sub * 4);
      dot1 = dx * qv.x + dy * qv.y + dz * qv.z + dw * qv.w;
    }
    {
      float4 qv = *(const float4*)(qsh + 2 * 128 + sub * 4);
      dot2 = dx * qv.x + dy * qv.y + dz * qv.z + dw * qv.w;
    }
    {
      float4 qv = *(const float4*)(qsh + 3 * 128 + sub * 4);
      dot3 = dx * qv.x + dy * qv.y + dz * qv.z + dw * qv.w;
    }
    #pragma unroll
    for (int m = 1; m <= 16; m <<= 1) {
      dot0 += __shfl_xor(dot0, m);
      dot1 += __shfl_xor(dot1, m);
      dot2 += __shfl_xor(dot2, m);
      dot3 += __shfl_xor(dot3, m);
    }
    if (sub < 4) {
      float v = (sub == 0) ? dot0 : (sub == 1) ? dot1 : (sub == 2) ? dot2 : dot3;
      scores[((size_t)(b * NH_ + kv * 4 + sub)) * L_ + l] = v * 0.08838834764831845f;
    }
  }
}

// ---------------- Kernel D: exact 2048th-largest via 3-pass radix select + row max ----
__global__ __launch_bounds__(256) void k_topk(const float* __restrict__ scores,
    float* __restrict__ kthM) {
  int row = blockIdx.x;                 // b*32+h
  const float* srow = scores + (size_t)row * L_;
  __shared__ unsigned bins[4096];
  __shared__ float smax[256];
  __shared__ unsigned chs[256];
  __shared__ unsigned sel_digit, sel_rank;
  int tid = threadIdx.x;

  // ---- pass 1: top 12 bits, plus global row max ----
  for (int i = tid; i < 4096; i += 256) bins[i] = 0;
  __syncthreads();
  float lm = -FLT_MAX;
  for (int l = tid; l < L_; l += 256) {
    float s = srow[l];
    lm = fmaxf(lm, s);
    bool always = (l < INIT_) || (l >= L_ - LOCAL_);
    if (!always) atomicAdd(&bins[f2key(s) >> 20], 1u);
  }
  smax[tid] = lm;
  __syncthreads();
  for (int off = 128; off > 0; off >>= 1) {
    if (tid < off) smax[tid] = fmaxf(smax[tid], smax[tid + off]);
    __syncthreads();
  }
  unsigned c = 0;
  for (int j = 0; j < 16; ++j) c += bins[tid * 16 + j];
  chs[tid] = c;
  __syncthreads();
  if (tid == 0) {
    unsigned K = HEAVY_, cum = 0; int cc = 255;
    for (; cc >= 0; --cc) { cum += chs[cc]; if (cum >= K) break; }
    unsigned rem = K - (cum - chs[cc]);
    unsigned cum2 = 0; int bb = cc * 16;
    for (int j = 15; j >= 0; --j) {
      cum2 += bins[cc * 16 + j];
      if (cum2 >= rem) { bb = cc * 16 + j; rem = rem - (cum2 - bins[cc * 16 + j]); break; }
    }
    sel_digit = (unsigned)bb; sel_rank = rem;
  }
  __syncthreads();
  unsigned d1 = sel_digit, K2 = sel_rank;
  __syncthreads();

  // ---- pass 2: bits 19:8 within d1 ----
  for (int i = tid; i < 4096; i += 256) bins[i] = 0;
  __syncthreads();
  for (int l = tid; l < L_; l += 256) {
    bool always = (l < INIT_) || (l >= L_ - LOCAL_);
    if (always) continue;
    unsigned u = f2key(srow[l]);
    if ((u >> 20) == d1) atomicAdd(&bins[(u >> 8) & 0xFFFu], 1u);
  }
  __syncthreads();
  c = 0;
  for (int j = 0; j < 16; ++j) c += bins[tid * 16 + j];
  chs[tid] = c;
  __syncthreads();
  if (tid == 0) {
    unsigned K = K2, cum = 0; int cc = 255;
    for (; cc >= 0; --cc) { cum += chs[cc]; if (cum >= K) break; }
    unsigned rem = K - (cum - chs[cc]);
    unsigned cum2 = 0; int bb = cc * 16;
    for (int j = 15; j >= 0; --j) {
      cum2 += bins[cc * 16 + j];
      if (cum2 >= rem) { bb = cc * 16 + j; rem = rem - (cum2 - bins[cc * 16 + j]); break; }
    }
    sel_digit = (unsigned)bb; sel_rank = rem;
  }
  __syncthreads();
  unsigned d2 = sel_digit, K3 = sel_rank;
  __syncthreads();

  // ---- pass 3: low 8 bits within (d1,d2) ----
  for (int i = tid; i < 4096; i += 256) bins[i] = 0;
  __syncthreads();
  unsigned pref = (d1 << 12) | d2;
  for (int l = tid; l < L_; l += 256) {
    bool always = (l < INIT_) || (l >= L_ - LOCAL_);
    if (always) continue;
    unsigned u = f2key(srow[l]);
    if ((u >> 8) == pref) atomicAdd(&bins[u & 0xFFu], 1u);
  }
  __syncthreads();
  if (tid == 0) {
    unsigned cum = 0; int bb = 0;
    for (int j = 255; j >= 0; --j) { cum += bins[j]; if (cum >= K3) { bb = j; break; } }
    unsigned ku = (d1 << 20) | (d2 << 8) | (unsigned)bb;
    kthM[row * 2 + 0] = key2f(ku);
    kthM[row * 2 + 1] = smax[0];
  }
}

// ---------------- Kernel E2: compact keep-list, then parallel V gather ----------------
// Phase 1: 4 waves scan 512 positions each; ballot-compact (idx, exp(s-M)) into LDS,
//          deterministic in-position order per wave segment.
// Phase 2: 8 half-waves (32 lanes x float4 = one 512B V row) walk the list round-robin.
__global__ __launch_bounds__(256) void k_pv(const float* __restrict__ scores,
    const float* __restrict__ kthM, const float* __restrict__ vcache,
    const float* __restrict__ vnew, float* __restrict__ partials) {
  int chunk = blockIdx.x, row = blockIdx.y;
  int b = row >> 5, h = row & 31, kv = h >> 2;
  int tid = threadIdx.x;
  int wave = tid >> 6, lane = tid & 63;
  float kth = kthM[row * 2 + 0], M = kthM[row * 2 + 1];
  const float* srow = scores + (size_t)row * L_;
  const float* vbase = vcache + ((size_t)(b * NKV_ + kv) * S_) * D_;
  const float* vnrow = vnew + (size_t)(b * NKV_ + kv) * D_;

  __shared__ int   s_idx[2048];
  __shared__ float s_w[2048];
  __shared__ int   s_cnt[4];
  __shared__ float s_acc[8][128];
  __shared__ float s_z[8];

  // ---- phase 1: scan + compact (wave w owns positions [chunk*2048 + w*512, +512)) ----
  int begin = chunk * CHUNK_ + wave * 512;
  int wcnt = 0;
  #pragma unroll
  for (int it = 0; it < 8; ++it) {
    int p = begin + it * 64 + lane;
    bool valid = (p < L_);
    float s = 0.0f;
    bool keep = false;
    if (valid) {
      s = srow[p];
      keep = (p < INIT_) || (p >= L_ - LOCAL_) || (s >= kth);
    }
    unsigned long long mask = __ballot(keep);
    if (keep) {
      int rank = __popcll(mask & ((1ull << lane) - 1ull));
      int slot = wave * 512 + wcnt + rank;
      s_idx[slot] = p;
      s_w[slot] = __expf(s - M) ;
    }
    wcnt += __popcll(mask);
  }
  if (lane == 0) s_cnt[wave] = wcnt;
  __syncthreads();

  // ---- phase 2: gather V rows; half-wave per row ----
  int hw = tid >> 5, sub = tid & 31;
  float4 acc = make_float4(0.f, 0.f, 0.f, 0.f);
  float z = 0.f;
  for (int seg = 0; seg < 4; ++seg) {
    int n = s_cnt[seg];
    for (int j = hw; j < n; j += 8) {
      int l = s_idx[seg * 512 + j];
      float w = s_w[seg * 512 + j];
      const float* vrow = (l < S_) ? (vbase + (size_t)l * D_) : vnrow;
      float4 v = *(const float4*)(vrow + sub * 4);
      float mn = fminf(fminf(v.x, v.y), fminf(v.z, v.w));
      float mx = fmaxf(fmaxf(v.x, v.y), fmaxf(v.z, v.w));
      #pragma unroll
      for (int m = 1; m <= 16; m <<= 1) {
        mn = fminf(mn, __shfl_xor(mn, m));
        mx = fmaxf(mx, __shfl_xor(mx, m));
      }
      float rng = mx - mn; rng = (rng == 0.0f) ? 1.0f : rng;
      float scale = 15.0f / rng;
      float s2 = rng * (1.0f / 15.0f);
      float vx = fmaf(fminf(fmaxf(rintf((v.x - mn) * scale), 0.0f), 15.0f), s2, mn);
      float vy = fmaf(fminf(fmaxf(rintf((v.y - mn) * scale), 0.0f), 15.0f), s2, mn);
      float vz = fmaf(fminf(fmaxf(rintf((v.z - mn) * scale), 0.0f), 15.0f), s2, mn);
      float vw = fmaf(fminf(fmaxf(rintf((v.w - mn) * scale), 0.0f), 15.0f), s2, mn);
      acc.x = fmaf(w, vx, acc.x);
      acc.y = fmaf(w, vy, acc.y);
      acc.z = fmaf(w, vz, acc.z);
      acc.w = fmaf(w, vw, acc.w);
      z += w;
    }
  }
  *(float4*)(&s_acc[hw][sub * 4]) = acc;
  if (sub == 0) s_z[hw] = z;
  __syncthreads();

  float* prow = partials + ((size_t)row * NCHUNK_ + chunk) * 129;
  if (tid < 128) {
    float a = 0.f;
    #pragma unroll
    for (int k = 0; k < 8; ++k) a += s_acc[k][tid];
    prow[tid] = a;
  } else if (tid == 128) {
    float zz = 0.f;
    #pragma unroll
    for (int k = 0; k < 8; ++k) zz += s_z[k];
    prow[128] = zz;
  }
}

// ---------------- Kernel E3: deterministic chunk reduce + normalize -------------------
__global__ __launch_bounds__(128) void k_fin(const float* __restrict__ partials,
    float* __restrict__ attn) {
  int row = blockIdx.x, d = threadIdx.x;
  float a = 0.f, z = 0.f;
  for (int c = 0; c < NCHUNK_; ++c) {
    const float* p = partials + ((size_t)row * NCHUNK_ + c) * 129;
    a += p[d];
    z += p[128];
  }
  attn[(size_t)row * 128 + d] = a / z;
}

// ---------------- Kernel F: output projection -----------------------------------------
__global__ __launch_bounds__(256) void k_out(const float* __restrict__ attn,
    const float* __restrict__ Wo, float* __restrict__ out) {
  int gw = (blockIdx.x * 256 + threadIdx.x) >> 6;   // 0..4095
  int lane = threadIdx.x & 63;
  const float* W = Wo + (size_t)gw * H_;
  float a0 = 0.f, a1 = 0.f, a2 = 0.f, a3 = 0.f;
  #pragma unroll 4
  for (int it = 0; it < 16; ++it) {
    int i = it * 256 + lane * 4;
    float4 w4 = *(const float4*)(W + i);
    float4 x0 = *(const float4*)(attn + 0 * H_ + i);
    float4 x1 = *(const float4*)(attn + 1 * H_ + i);
    float4 x2 = *(const float4*)(attn + 2 * H_ + i);
    float4 x3 = *(const float4*)(attn + 3 * H_ + i);
    a0 += w4.x * x0.x + w4.y * x0.y + w4.z * x0.z + w4.w * x0.w;
    a1 += w4.x * x1.x + w4.y * x1.y + w4.z * x1.z + w4.w * x1.w;
    a2 += w4.x * x2.x + w4.y * x2.y + w4.z * x2.z + w4.w * x2.w;
    a3 += w4.x * x3.x + w4.y * x3.y + w4.z * x3.z + w4.w * x3.w;
  }
  #pragma unroll
  for (int m = 1; m < 64; m <<= 1) {
    a0 += __shfl_xor(a0, m);
    a1 += __shfl_xor(a1, m);
    a2 += __shfl_xor(a2, m);
    a3 += __shfl_xor(a3, m);
  }
  if (lane < 4) {
    float v = (lane == 0) ? a0 : (lane == 1) ? a1 : (lane == 2) ? a2 : a3;
    out[(size_t)lane * H_ + gw] = v;
  }
}

extern "C" void kernel_launch(void* const* d_in, const int* in_sizes, int n_in,
                              void* d_out, int out_size, void* d_ws, size_t ws_size,
                              hipStream_t stream) {
  const float* hs     = (const float*)d_in[0];
  const float* kcache = (const float*)d_in[1];
  const float* vcache = (const float*)d_in[2];
  const float* cosv   = (const float*)d_in[3];
  const float* sinv   = (const float*)d_in[4];
  const float* Wq     = (const float*)d_in[5];
  const float* Wk     = (const float*)d_in[6];
  const float* Wv     = (const float*)d_in[7];
  const float* Wo     = (const float*)d_in[8];
  float* out = (float*)d_out;

  float* ws = (float*)d_ws;
  float* qraw     = ws;                      // 16384
  float* kraw     = qraw + 16384;            // 4096
  float* vnew     = kraw + 4096;             // 4096
  float* qrot     = vnew + 4096;             // 16384
  float* krot     = qrot + 16384;            // 4096
  float* scores   = krot + 4096;             // 4*32*16385 = 2097280
  float* kthM     = scores + 2097280;        // 256
  float* partials = kthM + 256;              // 128*9*129 = 148608
  float* attn     = partials + 148608;       // 16384
  (void)in_sizes; (void)n_in; (void)out_size; (void)ws_size; (void)attn;

  hipLaunchKernelGGL(k_proj,   dim3(1536),   dim3(256), 0, stream, hs, Wq, Wk, Wv, qraw, kraw, vnew);
  hipLaunchKernelGGL(k_rope,   dim3(160),    dim3(128), 0, stream, qraw, kraw, cosv, sinv, qrot, krot);
  hipLaunchKernelGGL(k_scores, dim3(33, 32), dim3(256), 0, stream, kcache, krot, qrot, scores);
  hipLaunchKernelGGL(k_topk,   dim3(128),    dim3(256), 0, stream, scores, kthM);
  hipLaunchKernelGGL(k_pv,     dim3(NCHUNK_, 128), dim3(256), 0, stream, scores, kthM, vcache, vnew, partials);
  hipLaunchKernelGGL(k_fin,    dim3(128),    dim3(128), 0, stream, partials, attn);
  hipLaunchKernelGGL(k_out,    dim3(1024),   dim3(256), 0, stream, attn, Wo, out);
}

// Round 3
// 241.588 us; speedup vs baseline: 2.1204x; 1.2763x over previous
//
#include <hip/hip_runtime.h>
#include <hip/hip_bf16.h>
#include <float.h>

#define B_ 4
#define NH_ 32
#define NKV_ 8
#define D_ 128
#define S_ 16384
#define L_ 16385
#define H_ 4096
#define INIT_ 128
#define LOCAL_ 128
#define HEAVY_ 2048
#define CHUNK_ 2048
#define NCHUNK_ 9   // ceil(16385/2048)

__device__ __forceinline__ unsigned f2key(float f) {
  unsigned u = __float_as_uint(f);
  return (u & 0x80000000u) ? ~u : (u | 0x80000000u);
}
__device__ __forceinline__ float key2f(unsigned k) {
  unsigned u = (k & 0x80000000u) ? (k & 0x7FFFFFFFu) : ~k;
  return __uint_as_float(u);
}

// packed min/max reduce over 32 lanes (6 shfl instead of 10).
// in: per-lane mn0/mx0. out: group-wide mn/mx in all lanes.
__device__ __forceinline__ void minmax32(int par, float mn0, float mx0, float& mn, float& mx) {
  float v = par ? -mx0 : mn0;
  float x = par ? mn0 : -mx0;
  v = fminf(v, __shfl_xor(x, 1));
  v = fminf(v, __shfl_xor(v, 2));
  v = fminf(v, __shfl_xor(v, 4));
  v = fminf(v, __shfl_xor(v, 8));
  v = fminf(v, __shfl_xor(v, 16));
  float t = __shfl_xor(v, 1);
  mn = par ? t : v;
  mx = -(par ? v : t);
}

// ---------------- Kernel A: q/k/v projections (one wave per output row, 4 batches) ----
__global__ __launch_bounds__(256) void k_proj(const float* __restrict__ hs,
    const float* __restrict__ Wq, const float* __restrict__ Wk, const float* __restrict__ Wv,
    float* __restrict__ qraw, float* __restrict__ kraw, float* __restrict__ vnew) {
  int gw = (blockIdx.x * 256 + threadIdx.x) >> 6;   // 0..6143
  int lane = threadIdx.x & 63;
  const float* W;
  if (gw < 4096)      W = Wq + (size_t)gw * H_;
  else if (gw < 5120) W = Wk + (size_t)(gw - 4096) * H_;
  else                W = Wv + (size_t)(gw - 5120) * H_;
  float a0 = 0.f, a1 = 0.f, a2 = 0.f, a3 = 0.f;
  #pragma unroll 4
  for (int it = 0; it < 16; ++it) {
    int h = it * 256 + lane * 4;
    float4 w4 = *(const float4*)(W + h);
    float4 x0 = *(const float4*)(hs + 0 * H_ + h);
    float4 x1 = *(const float4*)(hs + 1 * H_ + h);
    float4 x2 = *(const float4*)(hs + 2 * H_ + h);
    float4 x3 = *(const float4*)(hs + 3 * H_ + h);
    a0 += w4.x * x0.x + w4.y * x0.y + w4.z * x0.z + w4.w * x0.w;
    a1 += w4.x * x1.x + w4.y * x1.y + w4.z * x1.z + w4.w * x1.w;
    a2 += w4.x * x2.x + w4.y * x2.y + w4.z * x2.z + w4.w * x2.w;
    a3 += w4.x * x3.x + w4.y * x3.y + w4.z * x3.z + w4.w * x3.w;
  }
  // pair-merged 4-value butterfly: 7 shfl instead of 24
  float pa = (lane & 1) ? a1 : a0, xa = (lane & 1) ? a0 : a1;
  pa += __shfl_xor(xa, 1);
  float pb = (lane & 1) ? a3 : a2, xb = (lane & 1) ? a2 : a3;
  pb += __shfl_xor(xb, 1);
  float c = (lane & 2) ? pb : pa, xc = (lane & 2) ? pa : pb;
  c += __shfl_xor(xc, 2);
  c += __shfl_xor(c, 4);
  c += __shfl_xor(c, 8);
  c += __shfl_xor(c, 16);
  c += __shfl_xor(c, 32);
  if (lane < 4) {   // lane r holds sum of a_r
    if (gw < 4096)      qraw[(size_t)lane * H_ + gw] = c;
    else if (gw < 5120) kraw[(size_t)lane * 1024 + (gw - 4096)] = c;
    else                vnew[(size_t)lane * 1024 + (gw - 5120)] = c;
  }
}

// ---------------- Kernel B: RoPE on q and k_new (separate out buffers, no race) -------
__global__ __launch_bounds__(128) void k_rope(const float* __restrict__ qraw,
    const float* __restrict__ kraw, const float* __restrict__ cosv, const float* __restrict__ sinv,
    float* __restrict__ qrot, float* __restrict__ krot) {
  int bid = blockIdx.x;            // 0..159
  int b = bid / 40, r = bid % 40;
  int d = threadIdx.x;             // 0..127
  const float* src; float* dst;
  if (r < 32) { src = qraw + (size_t)b * H_ + r * 128; dst = qrot + (size_t)b * H_ + r * 128; }
  else { int kv = r - 32; src = kraw + (size_t)b * 1024 + kv * 128; dst = krot + (size_t)b * 1024 + kv * 128; }
  float x = src[d];
  float p = (d < 64) ? -src[d + 64] : src[d - 64];
  dst[d] = x * cosv[d] + p * sinv[d];
}

// ---------------- Kernel C: scores with 4-bit pseudo-quantized K ----------------------
// half-wave (32 lanes, float4 each) per K row; 4 GQA heads' dots per row.
// q rows held in registers; 12 shfl per row (was 30).
__global__ __launch_bounds__(256) void k_scores(const float* __restrict__ kcache,
    const float* __restrict__ krot, const float* __restrict__ qrot,
    float* __restrict__ scores) {
  int wave = threadIdx.x >> 6, lane = threadIdx.x & 63;
  int half = lane >> 5, sub = lane & 31;
  int par = sub & 1;
  int bkv = blockIdx.y; int b = bkv >> 3, kv = bkv & 7;
  __shared__ __align__(16) float qsh[512];
  for (int i = threadIdx.x; i < 512; i += 256)
    qsh[i] = qrot[(size_t)b * H_ + kv * 512 + i];
  __syncthreads();
  float4 q0 = *(const float4*)(qsh + 0 * 128 + sub * 4);
  float4 q1 = *(const float4*)(qsh + 1 * 128 + sub * 4);
  float4 q2 = *(const float4*)(qsh + 2 * 128 + sub * 4);
  float4 q3 = *(const float4*)(qsh + 3 * 128 + sub * 4);
  const float* kbase = kcache + ((size_t)(b * NKV_ + kv) * S_) * D_;
  float* srowbase = scores + (size_t)(b * NH_ + kv * 4) * L_;

  if (blockIdx.x < 32) {
    // fast path: all l in [base, base+512) < S_, no bounds checks
    int base = blockIdx.x * 512;
    #pragma unroll 2
    for (int it = 0; it < 64; ++it) {
      int l = base + it * 8 + wave * 2 + half;
      const float* krow = kbase + (size_t)l * D_;
      float4 kx = *(const float4*)(krow + sub * 4);
      float mn0 = fminf(fminf(kx.x, kx.y), fminf(kx.z, kx.w));
      float mx0 = fmaxf(fmaxf(kx.x, kx.y), fmaxf(kx.z, kx.w));
      float mn, mx;
      minmax32(par, mn0, mx0, mn, mx);
      float rng = mx - mn; rng = (rng == 0.0f) ? 1.0f : rng;
      float scale = 15.0f / rng;
      float s2 = rng * (1.0f / 15.0f);
      float dx = fmaf(fminf(fmaxf(rintf((kx.x - mn) * scale), 0.0f), 15.0f), s2, mn);
      float dy = fmaf(fminf(fmaxf(rintf((kx.y - mn) * scale), 0.0f), 15.0f), s2, mn);
      float dz = fmaf(fminf(fmaxf(rintf((kx.z - mn) * scale), 0.0f), 15.0f), s2, mn);
      float dw = fmaf(fminf(fmaxf(rintf((kx.w - mn) * scale), 0.0f), 15.0f), s2, mn);
      float d0 = dx * q0.x + dy * q0.y + dz * q0.z + dw * q0.w;
      float d1 = dx * q1.x + dy * q1.y + dz * q1.z + dw * q1.w;
      float d2 = dx * q2.x + dy * q2.y + dz * q2.z + dw * q2.w;
      float d3 = dx * q3.x + dy * q3.y + dz * q3.z + dw * q3.w;
      // pair-merged 4-dot butterfly: 6 shfl (was 20)
      float pa = par ? d1 : d0, xa = par ? d0 : d1;
      pa += __shfl_xor(xa, 1);
      float pb = par ? d3 : d2, xb = par ? d2 : d3;
      pb += __shfl_xor(xb, 1);
      float c = (sub & 2) ? pb : pa, xc = (sub & 2) ? pa : pb;
      c += __shfl_xor(xc, 2);
      c += __shfl_xor(c, 4);
      c += __shfl_xor(c, 8);
      c += __shfl_xor(c, 16);
      if (sub < 4) srowbase[(size_t)sub * L_ + l] = c * 0.08838834764831845f;
    }
  } else {
    // tail block: only l == 16384 (the new RoPE'd k row) is valid
    const float* knrow = krot + (size_t)(b * NKV_ + kv) * D_;
    if (wave == 0 && half == 0) {
      int l = S_;
      float4 kx = *(const float4*)(knrow + sub * 4);
      float mn0 = fminf(fminf(kx.x, kx.y), fminf(kx.z, kx.w));
      float mx0 = fmaxf(fmaxf(kx.x, kx.y), fmaxf(kx.z, kx.w));
      float mn, mx;
      minmax32(par, mn0, mx0, mn, mx);
      float rng = mx - mn; rng = (rng == 0.0f) ? 1.0f : rng;
      float scale = 15.0f / rng;
      float s2 = rng * (1.0f / 15.0f);
      float dx = fmaf(fminf(fmaxf(rintf((kx.x - mn) * scale), 0.0f), 15.0f), s2, mn);
      float dy = fmaf(fminf(fmaxf(rintf((kx.y - mn) * scale), 0.0f), 15.0f), s2, mn);
      float dz = fmaf(fminf(fmaxf(rintf((kx.z - mn) * scale), 0.0f), 15.0f), s2, mn);
      float dw = fmaf(fminf(fmaxf(rintf((kx.w - mn) * scale), 0.0f), 15.0f), s2, mn);
      float d0 = dx * q0.x + dy * q0.y + dz * q0.z + dw * q0.w;
      float d1 = dx * q1.x + dy * q1.y + dz * q1.z + dw * q1.w;
      float d2 = dx * q2.x + dy * q2.y + dz * q2.z + dw * q2.w;
      float d3 = dx * q3.x + dy * q3.y + dz * q3.z + dw * q3.w;
      float pa = par ? d1 : d0, xa = par ? d0 : d1;
      pa += __shfl_xor(xa, 1);
      float pb = par ? d3 : d2, xb = par ? d2 : d3;
      pb += __shfl_xor(xb, 1);
      float c = (sub & 2) ? pb : pa, xc = (sub & 2) ? pa : pb;
      c += __shfl_xor(xc, 2);
      c += __shfl_xor(c, 4);
      c += __shfl_xor(c, 8);
      c += __shfl_xor(c, 16);
      if (sub < 4) srowbase[(size_t)sub * L_ + l] = c * 0.08838834764831845f;
    }
  }
}

// ---------------- Kernel D: exact 2048th-largest via 3-pass radix select + row max ----
__global__ __launch_bounds__(512) void k_topk(const float* __restrict__ scores,
    float* __restrict__ kthM) {
  int row = blockIdx.x;                 // b*32+h
  const float* srow = scores + (size_t)row * L_;
  __shared__ unsigned bins[4096];
  __shared__ float smax[512];
  __shared__ unsigned chs[256];
  __shared__ unsigned sel_digit, sel_rank;
  int tid = threadIdx.x;

  // ---- pass 1: top 12 bits, plus global row max ----
  for (int i = tid; i < 4096; i += 512) bins[i] = 0;
  __syncthreads();
  float lm = -FLT_MAX;
  for (int l = tid; l < L_; l += 512) {
    float s = srow[l];
    lm = fmaxf(lm, s);
    bool always = (l < INIT_) || (l >= L_ - LOCAL_);
    if (!always) atomicAdd(&bins[f2key(s) >> 20], 1u);
  }
  smax[tid] = lm;
  __syncthreads();
  for (int off = 256; off > 0; off >>= 1) {
    if (tid < off) smax[tid] = fmaxf(smax[tid], smax[tid + off]);
    __syncthreads();
  }
  if (tid < 256) {
    unsigned c = 0;
    for (int j = 0; j < 16; ++j) c += bins[tid * 16 + j];
    chs[tid] = c;
  }
  __syncthreads();
  if (tid == 0) {
    unsigned K = HEAVY_, cum = 0; int cc = 255;
    for (; cc >= 0; --cc) { cum += chs[cc]; if (cum >= K) break; }
    unsigned rem = K - (cum - chs[cc]);
    unsigned cum2 = 0; int bb = cc * 16;
    for (int j = 15; j >= 0; --j) {
      cum2 += bins[cc * 16 + j];
      if (cum2 >= rem) { bb = cc * 16 + j; rem = rem - (cum2 - bins[cc * 16 + j]); break; }
    }
    sel_digit = (unsigned)bb; sel_rank = rem;
  }
  __syncthreads();
  unsigned d1 = sel_digit, K2 = sel_rank;
  __syncthreads();

  // ---- pass 2: bits 19:8 within d1 ----
  for (int i = tid; i < 4096; i += 512) bins[i] = 0;
  __syncthreads();
  for (int l = tid; l < L_; l += 512) {
    bool always = (l < INIT_) || (l >= L_ - LOCAL_);
    if (always) continue;
    unsigned u = f2key(srow[l]);
    if ((u >> 20) == d1) atomicAdd(&bins[(u >> 8) & 0xFFFu], 1u);
  }
  __syncthreads();
  if (tid < 256) {
    unsigned c = 0;
    for (int j = 0; j < 16; ++j) c += bins[tid * 16 + j];
    chs[tid] = c;
  }
  __syncthreads();
  if (tid == 0) {
    unsigned K = K2, cum = 0; int cc = 255;
    for (; cc >= 0; --cc) { cum += chs[cc]; if (cum >= K) break; }
    unsigned rem = K - (cum - chs[cc]);
    unsigned cum2 = 0; int bb = cc * 16;
    for (int j = 15; j >= 0; --j) {
      cum2 += bins[cc * 16 + j];
      if (cum2 >= rem) { bb = cc * 16 + j; rem = rem - (cum2 - bins[cc * 16 + j]); break; }
    }
    sel_digit = (unsigned)bb; sel_rank = rem;
  }
  __syncthreads();
  unsigned d2 = sel_digit, K3 = sel_rank;
  __syncthreads();

  // ---- pass 3: low 8 bits within (d1,d2) ----
  for (int i = tid; i < 4096; i += 512) bins[i] = 0;
  __syncthreads();
  unsigned pref = (d1 << 12) | d2;
  for (int l = tid; l < L_; l += 512) {
    bool always = (l < INIT_) || (l >= L_ - LOCAL_);
    if (always) continue;
    unsigned u = f2key(srow[l]);
    if ((u >> 8) == pref) atomicAdd(&bins[u & 0xFFu], 1u);
  }
  __syncthreads();
  if (tid == 0) {
    unsigned cum = 0; int bb = 0;
    for (int j = 255; j >= 0; --j) { cum += bins[j]; if (cum >= K3) { bb = j; break; } }
    unsigned ku = (d1 << 20) | (d2 << 8) | (unsigned)bb;
    kthM[row * 2 + 0] = key2f(ku);
    kthM[row * 2 + 1] = smax[0];
  }
}

// ---------------- Kernel E2: compact keep-list, then parallel V gather ----------------
__global__ __launch_bounds__(256) void k_pv(const float* __restrict__ scores,
    const float* __restrict__ kthM, const float* __restrict__ vcache,
    const float* __restrict__ vnew, float* __restrict__ partials) {
  int chunk = blockIdx.x, row = blockIdx.y;
  int b = row >> 5, h = row & 31, kv = h >> 2;
  int tid = threadIdx.x;
  int wave = tid >> 6, lane = tid & 63;
  float kth = kthM[row * 2 + 0], M = kthM[row * 2 + 1];
  const float* srow = scores + (size_t)row * L_;
  const float* vbase = vcache + ((size_t)(b * NKV_ + kv) * S_) * D_;
  const float* vnrow = vnew + (size_t)(b * NKV_ + kv) * D_;

  __shared__ int   s_idx[2048];
  __shared__ float s_w[2048];
  __shared__ int   s_cnt[4];
  __shared__ float s_acc[8][128];
  __shared__ float s_z[8];

  // ---- phase 1: scan + compact (wave w owns positions [chunk*2048 + w*512, +512)) ----
  int begin = chunk * CHUNK_ + wave * 512;
  int wcnt = 0;
  #pragma unroll
  for (int it = 0; it < 8; ++it) {
    int p = begin + it * 64 + lane;
    bool valid = (p < L_);
    float s = 0.0f;
    bool keep = false;
    if (valid) {
      s = srow[p];
      keep = (p < INIT_) || (p >= L_ - LOCAL_) || (s >= kth);
    }
    unsigned long long mask = __ballot(keep);
    if (keep) {
      int rank = __popcll(mask & ((1ull << lane) - 1ull));
      int slot = wave * 512 + wcnt + rank;
      s_idx[slot] = p;
      s_w[slot] = __expf(s - M);
    }
    wcnt += __popcll(mask);
  }
  if (lane == 0) s_cnt[wave] = wcnt;
  __syncthreads();

  // ---- phase 2: gather V rows; half-wave per row ----
  int hw = tid >> 5, sub = tid & 31;
  int par = sub & 1;
  float4 acc = make_float4(0.f, 0.f, 0.f, 0.f);
  float z = 0.f;
  for (int seg = 0; seg < 4; ++seg) {
    int n = s_cnt[seg];
    for (int j = hw; j < n; j += 8) {
      int l = s_idx[seg * 512 + j];
      float w = s_w[seg * 512 + j];
      const float* vrow = (l < S_) ? (vbase + (size_t)l * D_) : vnrow;
      float4 v = *(const float4*)(vrow + sub * 4);
      float mn0 = fminf(fminf(v.x, v.y), fminf(v.z, v.w));
      float mx0 = fmaxf(fmaxf(v.x, v.y), fmaxf(v.z, v.w));
      float mn, mx;
      minmax32(par, mn0, mx0, mn, mx);
      float rng = mx - mn; rng = (rng == 0.0f) ? 1.0f : rng;
      float scale = 15.0f / rng;
      float s2 = rng * (1.0f / 15.0f);
      float vx = fmaf(fminf(fmaxf(rintf((v.x - mn) * scale), 0.0f), 15.0f), s2, mn);
      float vy = fmaf(fminf(fmaxf(rintf((v.y - mn) * scale), 0.0f), 15.0f), s2, mn);
      float vz = fmaf(fminf(fmaxf(rintf((v.z - mn) * scale), 0.0f), 15.0f), s2, mn);
      float vw = fmaf(fminf(fmaxf(rintf((v.w - mn) * scale), 0.0f), 15.0f), s2, mn);
      acc.x = fmaf(w, vx, acc.x);
      acc.y = fmaf(w, vy, acc.y);
      acc.z = fmaf(w, vz, acc.z);
      acc.w = fmaf(w, vw, acc.w);
      z += w;
    }
  }
  *(float4*)(&s_acc[hw][sub * 4]) = acc;
  if (sub == 0) s_z[hw] = z;
  __syncthreads();

  float* prow = partials + ((size_t)row * NCHUNK_ + chunk) * 129;
  if (tid < 128) {
    float a = 0.f;
    #pragma unroll
    for (int k = 0; k < 8; ++k) a += s_acc[k][tid];
    prow[tid] = a;
  } else if (tid == 128) {
    float zz = 0.f;
    #pragma unroll
    for (int k = 0; k < 8; ++k) zz += s_z[k];
    prow[128] = zz;
  }
}

// ---------------- Kernel E3: deterministic chunk reduce + normalize -------------------
__global__ __launch_bounds__(128) void k_fin(const float* __restrict__ partials,
    float* __restrict__ attn) {
  int row = blockIdx.x, d = threadIdx.x;
  float a = 0.f, z = 0.f;
  for (int c = 0; c < NCHUNK_; ++c) {
    const float* p = partials + ((size_t)row * NCHUNK_ + c) * 129;
    a += p[d];
    z += p[128];
  }
  attn[(size_t)row * 128 + d] = a / z;
}

// ---------------- Kernel F: output projection -----------------------------------------
__global__ __launch_bounds__(256) void k_out(const float* __restrict__ attn,
    const float* __restrict__ Wo, float* __restrict__ out) {
  int gw = (blockIdx.x * 256 + threadIdx.x) >> 6;   // 0..4095
  int lane = threadIdx.x & 63;
  const float* W = Wo + (size_t)gw * H_;
  float a0 = 0.f, a1 = 0.f, a2 = 0.f, a3 = 0.f;
  #pragma unroll 4
  for (int it = 0; it < 16; ++it) {
    int i = it * 256 + lane * 4;
    float4 w4 = *(const float4*)(W + i);
    float4 x0 = *(const float4*)(attn + 0 * H_ + i);
    float4 x1 = *(const float4*)(attn + 1 * H_ + i);
    float4 x2 = *(const float4*)(attn + 2 * H_ + i);
    float4 x3 = *(const float4*)(attn + 3 * H_ + i);
    a0 += w4.x * x0.x + w4.y * x0.y + w4.z * x0.z + w4.w * x0.w;
    a1 += w4.x * x1.x + w4.y * x1.y + w4.z * x1.z + w4.w * x1.w;
    a2 += w4.x * x2.x + w4.y * x2.y + w4.z * x2.z + w4.w * x2.w;
    a3 += w4.x * x3.x + w4.y * x3.y + w4.z * x3.z + w4.w * x3.w;
  }
  float pa = (lane & 1) ? a1 : a0, xa = (lane & 1) ? a0 : a1;
  pa += __shfl_xor(xa, 1);
  float pb = (lane & 1) ? a3 : a2, xb = (lane & 1) ? a2 : a3;
  pb += __shfl_xor(xb, 1);
  float c = (lane & 2) ? pb : pa, xc = (lane & 2) ? pa : pb;
  c += __shfl_xor(xc, 2);
  c += __shfl_xor(c, 4);
  c += __shfl_xor(c, 8);
  c += __shfl_xor(c, 16);
  c += __shfl_xor(c, 32);
  if (lane < 4) out[(size_t)lane * H_ + gw] = c;
}

extern "C" void kernel_launch(void* const* d_in, const int* in_sizes, int n_in,
                              void* d_out, int out_size, void* d_ws, size_t ws_size,
                              hipStream_t stream) {
  const float* hs     = (const float*)d_in[0];
  const float* kcache = (const float*)d_in[1];
  const float* vcache = (const float*)d_in[2];
  const float* cosv   = (const float*)d_in[3];
  const float* sinv   = (const float*)d_in[4];
  const float* Wq     = (const float*)d_in[5];
  const float* Wk     = (const float*)d_in[6];
  const float* Wv     = (const float*)d_in[7];
  const float* Wo     = (const float*)d_in[8];
  float* out = (float*)d_out;

  float* ws = (float*)d_ws;
  float* qraw     = ws;                      // 16384
  float* kraw     = qraw + 16384;            // 4096
  float* vnew     = kraw + 4096;             // 4096
  float* qrot     = vnew + 4096;             // 16384
  float* krot     = qrot + 16384;            // 4096
  float* scores   = krot + 4096;             // 4*32*16385 = 2097280
  float* kthM     = scores + 2097280;        // 256
  float* partials = kthM + 256;              // 128*9*129 = 148608
  float* attn     = partials + 148608;       // 16384
  (void)in_sizes; (void)n_in; (void)out_size; (void)ws_size; (void)attn;

  hipLaunchKernelGGL(k_proj,   dim3(1536),   dim3(256), 0, stream, hs, Wq, Wk, Wv, qraw, kraw, vnew);
  hipLaunchKernelGGL(k_rope,   dim3(160),    dim3(128), 0, stream, qraw, kraw, cosv, sinv, qrot, krot);
  hipLaunchKernelGGL(k_scores, dim3(33, 32), dim3(256), 0, stream, kcache, krot, qrot, scores);
  hipLaunchKernelGGL(k_topk,   dim3(128),    dim3(512), 0, stream, scores, kthM);
  hipLaunchKernelGGL(k_pv,     dim3(NCHUNK_, 128), dim3(256), 0, stream, scores, kthM, vcache, vnew, partials);
  hipLaunchKernelGGL(k_fin,    dim3(128),    dim3(128), 0, stream, partials, attn);
  hipLaunchKernelGGL(k_out,    dim3(1024),   dim3(256), 0, stream, attn, Wo, out);
}

// Round 4
// 204.354 us; speedup vs baseline: 2.5067x; 1.1822x over previous
//
#include <hip/hip_runtime.h>
#include <hip/hip_bf16.h>
#include <float.h>

#define B_ 4
#define NH_ 32
#define NKV_ 8
#define D_ 128
#define S_ 16384
#define L_ 16385
#define H_ 4096
#define INIT_ 128
#define LOCAL_ 128
#define HEAVY_ 2048
#define CHUNK_ 2048
#define NCHUNK_ 9   // ceil(16385/2048)

__device__ __forceinline__ unsigned f2key(float f) {
  unsigned u = __float_as_uint(f);
  return (u & 0x80000000u) ? ~u : (u | 0x80000000u);
}
__device__ __forceinline__ float key2f(unsigned k) {
  unsigned u = (k & 0x80000000u) ? (k & 0x7FFFFFFFu) : ~k;
  return __uint_as_float(u);
}

// packed min/max reduce over 32 lanes (6 shfl instead of 10).
__device__ __forceinline__ void minmax32(int par, float mn0, float mx0, float& mn, float& mx) {
  float v = par ? -mx0 : mn0;
  float x = par ? mn0 : -mx0;
  v = fminf(v, __shfl_xor(x, 1));
  v = fminf(v, __shfl_xor(v, 2));
  v = fminf(v, __shfl_xor(v, 4));
  v = fminf(v, __shfl_xor(v, 8));
  v = fminf(v, __shfl_xor(v, 16));
  float t = __shfl_xor(v, 1);
  mn = par ? t : v;
  mx = -(par ? v : t);
}

// quantize K row fragment + 4 GQA dots + pair-merged reduce + store (lanes sub<4)
__device__ __forceinline__ void quant_dot_store(float4 kx,
    const float4& q0, const float4& q1, const float4& q2, const float4& q3,
    int sub, int par, float* __restrict__ srowbase, int l) {
  float mn0 = fminf(fminf(kx.x, kx.y), fminf(kx.z, kx.w));
  float mx0 = fmaxf(fmaxf(kx.x, kx.y), fmaxf(kx.z, kx.w));
  float mn, mx;
  minmax32(par, mn0, mx0, mn, mx);
  float rng = mx - mn; rng = (rng == 0.0f) ? 1.0f : rng;
  float scale = 15.0f / rng;          // IEEE divide: match reference rint boundaries
  float s2 = rng * (1.0f / 15.0f);
  float dx = fmaf(fminf(fmaxf(rintf((kx.x - mn) * scale), 0.0f), 15.0f), s2, mn);
  float dy = fmaf(fminf(fmaxf(rintf((kx.y - mn) * scale), 0.0f), 15.0f), s2, mn);
  float dz = fmaf(fminf(fmaxf(rintf((kx.z - mn) * scale), 0.0f), 15.0f), s2, mn);
  float dw = fmaf(fminf(fmaxf(rintf((kx.w - mn) * scale), 0.0f), 15.0f), s2, mn);
  float d0 = dx * q0.x + dy * q0.y + dz * q0.z + dw * q0.w;
  float d1 = dx * q1.x + dy * q1.y + dz * q1.z + dw * q1.w;
  float d2 = dx * q2.x + dy * q2.y + dz * q2.z + dw * q2.w;
  float d3 = dx * q3.x + dy * q3.y + dz * q3.z + dw * q3.w;
  // pair-merged 4-dot butterfly: 6 shfl
  float pa = par ? d1 : d0, xa = par ? d0 : d1;
  pa += __shfl_xor(xa, 1);
  float pb = par ? d3 : d2, xb = par ? d2 : d3;
  pb += __shfl_xor(xb, 1);
  float c = (sub & 2) ? pb : pa, xc = (sub & 2) ? pa : pb;
  c += __shfl_xor(xc, 2);
  c += __shfl_xor(c, 4);
  c += __shfl_xor(c, 8);
  c += __shfl_xor(c, 16);
  if (sub < 4) srowbase[(size_t)sub * L_ + l] = c * 0.08838834764831845f;
}

// ---------------- Kernel A: q/k/v projections (one wave per output row, 4 batches) ----
__global__ __launch_bounds__(256) void k_proj(const float* __restrict__ hs,
    const float* __restrict__ Wq, const float* __restrict__ Wk, const float* __restrict__ Wv,
    float* __restrict__ qraw, float* __restrict__ kraw, float* __restrict__ vnew) {
  int gw = (blockIdx.x * 256 + threadIdx.x) >> 6;   // 0..6143
  int lane = threadIdx.x & 63;
  const float* W;
  if (gw < 4096)      W = Wq + (size_t)gw * H_;
  else if (gw < 5120) W = Wk + (size_t)(gw - 4096) * H_;
  else                W = Wv + (size_t)(gw - 5120) * H_;
  float a0 = 0.f, a1 = 0.f, a2 = 0.f, a3 = 0.f;
  #pragma unroll 4
  for (int it = 0; it < 16; ++it) {
    int h = it * 256 + lane * 4;
    float4 w4 = *(const float4*)(W + h);
    float4 x0 = *(const float4*)(hs + 0 * H_ + h);
    float4 x1 = *(const float4*)(hs + 1 * H_ + h);
    float4 x2 = *(const float4*)(hs + 2 * H_ + h);
    float4 x3 = *(const float4*)(hs + 3 * H_ + h);
    a0 += w4.x * x0.x + w4.y * x0.y + w4.z * x0.z + w4.w * x0.w;
    a1 += w4.x * x1.x + w4.y * x1.y + w4.z * x1.z + w4.w * x1.w;
    a2 += w4.x * x2.x + w4.y * x2.y + w4.z * x2.z + w4.w * x2.w;
    a3 += w4.x * x3.x + w4.y * x3.y + w4.z * x3.z + w4.w * x3.w;
  }
  float pa = (lane & 1) ? a1 : a0, xa = (lane & 1) ? a0 : a1;
  pa += __shfl_xor(xa, 1);
  float pb = (lane & 1) ? a3 : a2, xb = (lane & 1) ? a2 : a3;
  pb += __shfl_xor(xb, 1);
  float c = (lane & 2) ? pb : pa, xc = (lane & 2) ? pa : pb;
  c += __shfl_xor(xc, 2);
  c += __shfl_xor(c, 4);
  c += __shfl_xor(c, 8);
  c += __shfl_xor(c, 16);
  c += __shfl_xor(c, 32);
  if (lane < 4) {   // lane r holds sum of batch r
    if (gw < 4096)      qraw[(size_t)lane * H_ + gw] = c;
    else if (gw < 5120) kraw[(size_t)lane * 1024 + (gw - 4096)] = c;
    else                vnew[(size_t)lane * 1024 + (gw - 5120)] = c;
  }
}

// ---------------- Kernel C: fused RoPE + scores with 4-bit pseudo-quantized K ---------
// grid (64, 32): 256 K rows per block; block 63 also handles the new k row (l=16384).
__global__ __launch_bounds__(256) void k_scores(const float* __restrict__ kcache,
    const float* __restrict__ kraw, const float* __restrict__ qraw,
    const float* __restrict__ cosv, const float* __restrict__ sinv,
    float* __restrict__ scores) {
  int wave = threadIdx.x >> 6, lane = threadIdx.x & 63;
  int half = lane >> 5, sub = lane & 31;
  int par = sub & 1;
  int bkv = blockIdx.y; int b = bkv >> 3, kv = bkv & 7;
  __shared__ __align__(16) float qsh[512];
  const float* qbase = qraw + (size_t)b * H_ + kv * 512;
  for (int i = threadIdx.x; i < 512; i += 256) {
    int d = i & 127;
    int j = (i & ~127) | ((d + 64) & 127);
    float x = qbase[i];
    float y = qbase[j];
    float p = (d < 64) ? -y : y;
    qsh[i] = x * cosv[d] + p * sinv[d];
  }
  __syncthreads();
  float4 q0 = *(const float4*)(qsh + 0 * 128 + sub * 4);
  float4 q1 = *(const float4*)(qsh + 1 * 128 + sub * 4);
  float4 q2 = *(const float4*)(qsh + 2 * 128 + sub * 4);
  float4 q3 = *(const float4*)(qsh + 3 * 128 + sub * 4);
  const float* kbase = kcache + ((size_t)(b * NKV_ + kv) * S_) * D_;
  float* srowbase = scores + (size_t)(b * NH_ + kv * 4) * L_;

  int base = blockIdx.x * 256;
  #pragma unroll 2
  for (int it = 0; it < 32; ++it) {
    int l = base + it * 8 + wave * 2 + half;
    const float* krow = kbase + (size_t)l * D_;
    float4 kx = *(const float4*)(krow + sub * 4);
    quant_dot_store(kx, q0, q1, q2, q3, sub, par, srowbase, l);
  }
  // tail: new RoPE'd k row at l = 16384, handled by block 63 half-wave 0
  if (blockIdx.x == 63 && wave == 0 && half == 0) {
    const float* kb = kraw + (size_t)b * 1024 + kv * 128;
    float el[4];
    #pragma unroll
    for (int e = 0; e < 4; ++e) {
      int d = sub * 4 + e;
      float x = kb[d];
      float y = kb[(d + 64) & 127];
      float p = (d < 64) ? -y : y;
      el[e] = x * cosv[d] + p * sinv[d];
    }
    float4 kx = make_float4(el[0], el[1], el[2], el[3]);
    quant_dot_store(kx, q0, q1, q2, q3, sub, par, srowbase, S_);
  }
}

// ---------------- Kernel D: exact 2048th-largest, register-resident radix select ------
// 512 threads; each holds 32 keys in VGPRs. Passes 2-3 rescan registers (no reloads).
__global__ __launch_bounds__(512) void k_topk(const float* __restrict__ scores,
    float* __restrict__ kthM) {
  int row = blockIdx.x;                 // b*32+h
  const float* srow = scores + (size_t)row * L_;
  __shared__ unsigned bins[4096];
  __shared__ unsigned chs[256];
  __shared__ float wmax[8];
  __shared__ unsigned sel_digit, sel_rank;
  int tid = threadIdx.x;
  int wid = tid >> 6, lane = tid & 63;

  // ---- load 32 values into registers; fold row max (incl. l=16384 broadcast) ----
  unsigned keys[32];
  float lm = srow[16384];               // always-region: in max, never in histograms
  #pragma unroll
  for (int j = 0; j < 32; ++j) {
    float s = srow[j * 512 + tid];
    lm = fmaxf(lm, s);
    keys[j] = f2key(s);
  }
  #pragma unroll
  for (int m = 1; m < 64; m <<= 1) lm = fmaxf(lm, __shfl_xor(lm, m));
  if (lane == 0) wmax[wid] = lm;

  // ---- pass 1: top 12 bits ----
  for (int i = tid; i < 4096; i += 512) bins[i] = 0;
  __syncthreads();
  #pragma unroll
  for (int j = 0; j < 32; ++j) {
    // always-region: j==0 & tid<128 (l<128), j==31 & tid>=385 (l>=16257)
    if ((j != 0 || tid >= 128) && (j != 31 || tid < 385))
      atomicAdd(&bins[keys[j] >> 20], 1u);
  }
  __syncthreads();
  if (tid < 256) {
    unsigned c = 0;
    #pragma unroll
    for (int j = 0; j < 16; ++j) c += bins[tid * 16 + j];
    chs[tid] = c;
  }
  __syncthreads();
  if (tid == 0) {
    unsigned K = HEAVY_, cum = 0; int cc = 255;
    for (; cc >= 0; --cc) { cum += chs[cc]; if (cum >= K) break; }
    unsigned rem = K - (cum - chs[cc]);
    unsigned cum2 = 0; int bb = cc * 16;
    for (int j = 15; j >= 0; --j) {
      cum2 += bins[cc * 16 + j];
      if (cum2 >= rem) { bb = cc * 16 + j; rem = rem - (cum2 - bins[cc * 16 + j]); break; }
    }
    sel_digit = (unsigned)bb; sel_rank = rem;
  }
  __syncthreads();
  unsigned d1 = sel_digit, K2 = sel_rank;
  __syncthreads();

  // ---- pass 2: bits 19:8 within d1 (registers only) ----
  for (int i = tid; i < 4096; i += 512) bins[i] = 0;
  __syncthreads();
  #pragma unroll
  for (int j = 0; j < 32; ++j) {
    if ((j != 0 || tid >= 128) && (j != 31 || tid < 385)) {
      unsigned u = keys[j];
      if ((u >> 20) == d1) atomicAdd(&bins[(u >> 8) & 0xFFFu], 1u);
    }
  }
  __syncthreads();
  if (tid < 256) {
    unsigned c = 0;
    #pragma unroll
    for (int j = 0; j < 16; ++j) c += bins[tid * 16 + j];
    chs[tid] = c;
  }
  __syncthreads();
  if (tid == 0) {
    unsigned K = K2, cum = 0; int cc = 255;
    for (; cc >= 0; --cc) { cum += chs[cc]; if (cum >= K) break; }
    unsigned rem = K - (cum - chs[cc]);
    unsigned cum2 = 0; int bb = cc * 16;
    for (int j = 15; j >= 0; --j) {
      cum2 += bins[cc * 16 + j];
      if (cum2 >= rem) { bb = cc * 16 + j; rem = rem - (cum2 - bins[cc * 16 + j]); break; }
    }
    sel_digit = (unsigned)bb; sel_rank = rem;
  }
  __syncthreads();
  unsigned d2 = sel_digit, K3 = sel_rank;
  __syncthreads();

  // ---- pass 3: low 8 bits within (d1,d2) (registers only) ----
  for (int i = tid; i < 256; i += 512) { }   // bins[0..255] reused
  if (tid < 256) bins[tid] = 0;
  __syncthreads();
  unsigned pref = (d1 << 12) | d2;
  #pragma unroll
  for (int j = 0; j < 32; ++j) {
    if ((j != 0 || tid >= 128) && (j != 31 || tid < 385)) {
      unsigned u = keys[j];
      if ((u >> 8) == pref) atomicAdd(&bins[u & 0xFFu], 1u);
    }
  }
  __syncthreads();
  if (tid == 0) {
    unsigned cum = 0; int bb = 0;
    for (int j = 255; j >= 0; --j) { cum += bins[j]; if (cum >= K3) { bb = j; break; } }
    unsigned ku = (d1 << 20) | (d2 << 8) | (unsigned)bb;
    float m = wmax[0];
    #pragma unroll
    for (int k = 1; k < 8; ++k) m = fmaxf(m, wmax[k]);
    kthM[row * 2 + 0] = key2f(ku);
    kthM[row * 2 + 1] = m;
  }
}

// ---------------- Kernel E2: compact keep-list, then parallel V gather ----------------
__global__ __launch_bounds__(256) void k_pv(const float* __restrict__ scores,
    const float* __restrict__ kthM, const float* __restrict__ vcache,
    const float* __restrict__ vnew, float* __restrict__ partials) {
  int chunk = blockIdx.x, row = blockIdx.y;
  int b = row >> 5, h = row & 31, kv = h >> 2;
  int tid = threadIdx.x;
  int wave = tid >> 6, lane = tid & 63;
  float kth = kthM[row * 2 + 0], M = kthM[row * 2 + 1];
  const float* srow = scores + (size_t)row * L_;
  const float* vbase = vcache + ((size_t)(b * NKV_ + kv) * S_) * D_;
  const float* vnrow = vnew + (size_t)(b * NKV_ + kv) * D_;

  __shared__ int   s_idx[2048];
  __shared__ float s_w[2048];
  __shared__ int   s_cnt[4];
  __shared__ float s_acc[8][128];
  __shared__ float s_z[8];

  // ---- phase 1: scan + compact ----
  int begin = chunk * CHUNK_ + wave * 512;
  int wcnt = 0;
  #pragma unroll
  for (int it = 0; it < 8; ++it) {
    int p = begin + it * 64 + lane;
    bool valid = (p < L_);
    float s = 0.0f;
    bool keep = false;
    if (valid) {
      s = srow[p];
      keep = (p < INIT_) || (p >= L_ - LOCAL_) || (s >= kth);
    }
    unsigned long long mask = __ballot(keep);
    if (keep) {
      int rank = __popcll(mask & ((1ull << lane) - 1ull));
      int slot = wave * 512 + wcnt + rank;
      s_idx[slot] = p;
      s_w[slot] = __expf(s - M);
    }
    wcnt += __popcll(mask);
  }
  if (lane == 0) s_cnt[wave] = wcnt;
  __syncthreads();

  // ---- phase 2: gather V rows; half-wave per row ----
  int hw = tid >> 5, sub = tid & 31;
  int par = sub & 1;
  float4 acc = make_float4(0.f, 0.f, 0.f, 0.f);
  float z = 0.f;
  for (int seg = 0; seg < 4; ++seg) {
    int n = s_cnt[seg];
    for (int j = hw; j < n; j += 8) {
      int l = s_idx[seg * 512 + j];
      float w = s_w[seg * 512 + j];
      const float* vrow = (l < S_) ? (vbase + (size_t)l * D_) : vnrow;
      float4 v = *(const float4*)(vrow + sub * 4);
      float mn0 = fminf(fminf(v.x, v.y), fminf(v.z, v.w));
      float mx0 = fmaxf(fmaxf(v.x, v.y), fmaxf(v.z, v.w));
      float mn, mx;
      minmax32(par, mn0, mx0, mn, mx);
      float rng = mx - mn; rng = (rng == 0.0f) ? 1.0f : rng;
      float scale = 15.0f / rng;
      float s2 = rng * (1.0f / 15.0f);
      float vx = fmaf(fminf(fmaxf(rintf((v.x - mn) * scale), 0.0f), 15.0f), s2, mn);
      float vy = fmaf(fminf(fmaxf(rintf((v.y - mn) * scale), 0.0f), 15.0f), s2, mn);
      float vz = fmaf(fminf(fmaxf(rintf((v.z - mn) * scale), 0.0f), 15.0f), s2, mn);
      float vw = fmaf(fminf(fmaxf(rintf((v.w - mn) * scale), 0.0f), 15.0f), s2, mn);
      acc.x = fmaf(w, vx, acc.x);
      acc.y = fmaf(w, vy, acc.y);
      acc.z = fmaf(w, vz, acc.z);
      acc.w = fmaf(w, vw, acc.w);
      z += w;
    }
  }
  *(float4*)(&s_acc[hw][sub * 4]) = acc;
  if (sub == 0) s_z[hw] = z;
  __syncthreads();

  float* prow = partials + ((size_t)row * NCHUNK_ + chunk) * 129;
  if (tid < 128) {
    float a = 0.f;
    #pragma unroll
    for (int k = 0; k < 8; ++k) a += s_acc[k][tid];
    prow[tid] = a;
  } else if (tid == 128) {
    float zz = 0.f;
    #pragma unroll
    for (int k = 0; k < 8; ++k) zz += s_z[k];
    prow[128] = zz;
  }
}

// ---------------- Kernel E3: deterministic chunk reduce + normalize -------------------
__global__ __launch_bounds__(128) void k_fin(const float* __restrict__ partials,
    float* __restrict__ attn) {
  int row = blockIdx.x, d = threadIdx.x;
  float a = 0.f, z = 0.f;
  for (int c = 0; c < NCHUNK_; ++c) {
    const float* p = partials + ((size_t)row * NCHUNK_ + c) * 129;
    a += p[d];
    z += p[128];
  }
  attn[(size_t)row * 128 + d] = a / z;
}

// ---------------- Kernel F: output projection -----------------------------------------
__global__ __launch_bounds__(256) void k_out(const float* __restrict__ attn,
    const float* __restrict__ Wo, float* __restrict__ out) {
  int gw = (blockIdx.x * 256 + threadIdx.x) >> 6;   // 0..4095
  int lane = threadIdx.x & 63;
  const float* W = Wo + (size_t)gw * H_;
  float a0 = 0.f, a1 = 0.f, a2 = 0.f, a3 = 0.f;
  #pragma unroll 4
  for (int it = 0; it < 16; ++it) {
    int i = it * 256 + lane * 4;
    float4 w4 = *(const float4*)(W + i);
    float4 x0 = *(const float4*)(attn + 0 * H_ + i);
    float4 x1 = *(const float4*)(attn + 1 * H_ + i);
    float4 x2 = *(const float4*)(attn + 2 * H_ + i);
    float4 x3 = *(const float4*)(attn + 3 * H_ + i);
    a0 += w4.x * x0.x + w4.y * x0.y + w4.z * x0.z + w4.w * x0.w;
    a1 += w4.x * x1.x + w4.y * x1.y + w4.z * x1.z + w4.w * x1.w;
    a2 += w4.x * x2.x + w4.y * x2.y + w4.z * x2.z + w4.w * x2.w;
    a3 += w4.x * x3.x + w4.y * x3.y + w4.z * x3.z + w4.w * x3.w;
  }
  float pa = (lane & 1) ? a1 : a0, xa = (lane & 1) ? a0 : a1;
  pa += __shfl_xor(xa, 1);
  float pb = (lane & 1) ? a3 : a2, xb = (lane & 1) ? a2 : a3;
  pb += __shfl_xor(xb, 1);
  float c = (lane & 2) ? pb : pa, xc = (lane & 2) ? pa : pb;
  c += __shfl_xor(xc, 2);
  c += __shfl_xor(c, 4);
  c += __shfl_xor(c, 8);
  c += __shfl_xor(c, 16);
  c += __shfl_xor(c, 32);
  if (lane < 4) out[(size_t)lane * H_ + gw] = c;
}

extern "C" void kernel_launch(void* const* d_in, const int* in_sizes, int n_in,
                              void* d_out, int out_size, void* d_ws, size_t ws_size,
                              hipStream_t stream) {
  const float* hs     = (const float*)d_in[0];
  const float* kcache = (const float*)d_in[1];
  const float* vcache = (const float*)d_in[2];
  const float* cosv   = (const float*)d_in[3];
  const float* sinv   = (const float*)d_in[4];
  const float* Wq     = (const float*)d_in[5];
  const float* Wk     = (const float*)d_in[6];
  const float* Wv     = (const float*)d_in[7];
  const float* Wo     = (const float*)d_in[8];
  float* out = (float*)d_out;

  float* ws = (float*)d_ws;
  float* qraw     = ws;                      // 16384
  float* kraw     = qraw + 16384;            // 4096
  float* vnew     = kraw + 4096;             // 4096
  float* scores   = vnew + 4096;             // 4*32*16385 = 2097280
  float* kthM     = scores + 2097280;        // 256
  float* partials = kthM + 256;              // 128*9*129 = 148608
  float* attn     = partials + 148608;       // 16384
  (void)in_sizes; (void)n_in; (void)out_size; (void)ws_size;

  hipLaunchKernelGGL(k_proj,   dim3(1536),   dim3(256), 0, stream, hs, Wq, Wk, Wv, qraw, kraw, vnew);
  hipLaunchKernelGGL(k_scores, dim3(64, 32), dim3(256), 0, stream, kcache, kraw, qraw, cosv, sinv, scores);
  hipLaunchKernelGGL(k_topk,   dim3(128),    dim3(512), 0, stream, scores, kthM);
  hipLaunchKernelGGL(k_pv,     dim3(NCHUNK_, 128), dim3(256), 0, stream, scores, kthM, vcache, vnew, partials);
  hipLaunchKernelGGL(k_fin,    dim3(128),    dim3(128), 0, stream, partials, attn);
  hipLaunchKernelGGL(k_out,    dim3(1024),   dim3(256), 0, stream, attn, Wo, out);
}